// Round 3
// baseline (331.478 us; speedup 1.0000x reference)
//
#include <hip/hip_runtime.h>
#include <hip/hip_bf16.h>
#include <cstdint>

typedef uint16_t u16;
typedef __attribute__((ext_vector_type(8))) __bf16 bf16x8;
typedef __attribute__((ext_vector_type(4))) short s16x4;
typedef __attribute__((ext_vector_type(8))) short s16x8;
typedef __attribute__((ext_vector_type(4))) float f32x4;

#define MFMA(a, b, c) __builtin_amdgcn_mfma_f32_16x16x32_bf16((a), (b), (c), 0, 0, 0)

__device__ __forceinline__ u16 f2bf(float f) {
  union { float f; uint32_t u; } v; v.f = f;
  uint32_t u = v.u;
  return (u16)((u + 0x7FFFu + ((u >> 16) & 1u)) >> 16);
}
__device__ __forceinline__ float bf2f(u16 s) {
  union { uint32_t u; float f; } v; v.u = ((uint32_t)s) << 16;
  return v.f;
}

union U8 { s16x8 s; bf16x8 b; };

// load 8 consecutive f32 -> bf16x8
__device__ __forceinline__ bf16x8 ld_bf8(const float* __restrict__ p) {
  float4 v0 = *(const float4*)p;
  float4 v1 = *(const float4*)(p + 4);
  U8 u;
  u.s[0] = (short)f2bf(v0.x); u.s[1] = (short)f2bf(v0.y);
  u.s[2] = (short)f2bf(v0.z); u.s[3] = (short)f2bf(v0.w);
  u.s[4] = (short)f2bf(v1.x); u.s[5] = (short)f2bf(v1.y);
  u.s[6] = (short)f2bf(v1.z); u.s[7] = (short)f2bf(v1.w);
  return u.b;
}
// load 8 f32 strided by 128 (Wa column) -> bf16x8
__device__ __forceinline__ bf16x8 ld_bf8_s128(const float* __restrict__ p) {
  U8 u;
  #pragma unroll
  for (int e = 0; e < 8; ++e) u.s[e] = (short)f2bf(p[(size_t)e * 128]);
  return u.b;
}

// ---------------- prep: bias table + per-head temperature (1 block) ----------------
__global__ void k_tb(const float* __restrict__ rpos, const float* __restrict__ w1,
                     const float* __restrict__ b1, const float* __restrict__ w2,
                     const float* __restrict__ ls, const int* __restrict__ ridx,
                     float* __restrict__ biasT, float* __restrict__ temp) {
  __shared__ float tbl[225][4];
  int t = threadIdx.x;
  if (t < 225) {
    float x0 = rpos[t * 2 + 0], x1 = rpos[t * 2 + 1];
    float a0 = 0.f, a1 = 0.f, a2 = 0.f, a3 = 0.f;
    for (int c = 0; c < 512; ++c) {
      float hv = fmaxf(fmaf(x0, w1[c], fmaf(x1, w1[512 + c], b1[c])), 0.f);
      a0 = fmaf(hv, w2[c * 4 + 0], a0);
      a1 = fmaf(hv, w2[c * 4 + 1], a1);
      a2 = fmaf(hv, w2[c * 4 + 2], a2);
      a3 = fmaf(hv, w2[c * 4 + 3], a3);
    }
    tbl[t][0] = a0; tbl[t][1] = a1; tbl[t][2] = a2; tbl[t][3] = a3;
  }
  if (t < 4) temp[t] = expf(fminf(ls[t], 4.6051701859880914f));
  __syncthreads();
  // biasT[h][q][p] = 16*sigmoid(tbl[ridx[ii][jj]][h]), einops scramble
  for (int it = 0; it < 64; ++it) {
    int gid = it * 256 + t;                     // < 16384
    int h = gid >> 12;
    int rem = gid & 4095;
    int q = rem >> 6, p = rem & 63;
    int ii = ((p >> 3) << 3) + (q >> 3);
    int jj = ((p & 7) << 3) + (q & 7);
    int ri = ridx[ii * 64 + jj];
    float v = tbl[ri][h];
    biasT[gid] = 16.f / (1.f + expf(-v));
  }
}

// ---------------- prep: Gram-type matrices (16 blocks = h x t) ----------------
//  t=0: M = Wq_h Wk_h^T  -> BigB rows [h*384 + 0   + l][k], aug k=128: (Wk qb)_l
//  t=1: Gq = Wq Wq^T     -> BigB rows [h*384 + 128 + l][k], aug: 2(Wq qb)_l
//  t=2: Gk = Wk Wk^T     -> BigB rows [h*384 + 256 + l][k], aug: 0
//  t=3: N  = Wv_h Wa_h   -> NT rows [h*128 + c][k=a], aug k=128: w_h[c]=vb.Wa_h[:,c]
__global__ void k_gram(const float* __restrict__ Wq, const float* __restrict__ Wk,
                       const float* __restrict__ Wv, const float* __restrict__ Wa,
                       const float* __restrict__ Qb, const float* __restrict__ Vb,
                       u16* __restrict__ BigB, u16* __restrict__ NT,
                       float* __restrict__ cq4) {
  const int h = blockIdx.x >> 2, t = blockIdx.x & 3;
  const int tid = threadIdx.x;
  const int wid = tid >> 6, lane = tid & 63;
  const int l15 = lane & 15, lk4 = (lane >> 4) << 2, lk8 = (lane >> 4) << 3;
  const float* Am = (t == 3) ? Wv : (t == 2) ? Wk : Wq;
  const float* Bm = (t == 1) ? Wq : Wk;     // t==3 handled separately
  const f32x4 zf4 = {0.f, 0.f, 0.f, 0.f};
  f32x4 acc[2][8];
  #pragma unroll
  for (int mm = 0; mm < 2; ++mm)
    #pragma unroll
    for (int nn = 0; nn < 8; ++nn) acc[mm][nn] = zf4;
  for (int ks = 0; ks < 12; ++ks) {
    const int koff = h * 384 + ks * 32 + lk8;
    bf16x8 a[2], bw[8];
    #pragma unroll
    for (int mm = 0; mm < 2; ++mm)
      a[mm] = ld_bf8(&Am[(size_t)(wid * 32 + mm * 16 + l15) * 1536 + koff]);
    if (t < 3) {
      #pragma unroll
      for (int nn = 0; nn < 8; ++nn)
        bw[nn] = ld_bf8(&Bm[(size_t)(nn * 16 + l15) * 1536 + koff]);
    } else {
      #pragma unroll
      for (int nn = 0; nn < 8; ++nn)
        bw[nn] = ld_bf8_s128(&Wa[(size_t)koff * 128 + nn * 16 + l15]);
    }
    #pragma unroll
    for (int nn = 0; nn < 8; ++nn)
      #pragma unroll
      for (int mm = 0; mm < 2; ++mm)
        acc[mm][nn] = MFMA(a[mm], bw[nn], acc[mm][nn]);
  }
  #pragma unroll
  for (int mm = 0; mm < 2; ++mm) {
    const int k0 = wid * 32 + mm * 16 + lk4;
    #pragma unroll
    for (int nn = 0; nn < 8; ++nn) {
      const int l = nn * 16 + l15;
      s16x4 u;
      u[0] = (short)f2bf(acc[mm][nn][0]); u[1] = (short)f2bf(acc[mm][nn][1]);
      u[2] = (short)f2bf(acc[mm][nn][2]); u[3] = (short)f2bf(acc[mm][nn][3]);
      if (t < 3) *(s16x4*)&BigB[(size_t)(h * 384 + t * 128 + l) * 160 + k0] = u;
      else       *(s16x4*)&NT[(size_t)(h * 128 + l) * 160 + k0] = u;
    }
  }
  // augmented column k=128 + zero-fill 129..159
  if (t < 3) {
    for (int l = tid; l < 128; l += 256) {
      float s = 0.f;
      if (t == 0) { for (int f = 0; f < 384; ++f) s += Wk[(size_t)l * 1536 + h * 384 + f] * Qb[h * 384 + f]; }
      else if (t == 1) { for (int f = 0; f < 384; ++f) s += 2.f * Wq[(size_t)l * 1536 + h * 384 + f] * Qb[h * 384 + f]; }
      u16* row = &BigB[(size_t)(h * 384 + t * 128 + l) * 160];
      row[128] = f2bf(s);
      for (int e = 129; e < 160; ++e) row[e] = 0;
    }
    if (t == 0 && tid == 0) {
      float s = 0.f;
      for (int f = 0; f < 384; ++f) s += Qb[h * 384 + f] * Qb[h * 384 + f];
      cq4[h] = s;
    }
  } else {
    for (int c = tid; c < 128; c += 256) {
      float s = 0.f;
      for (int f = 0; f < 384; ++f) s += Vb[h * 384 + f] * Wa[(size_t)(h * 384 + f) * 128 + c];
      u16* row = &NT[(size_t)(h * 128 + c) * 160];
      row[128] = f2bf(s);
      for (int e = 129; e < 160; ++e) row[e] = 0;
    }
  }
}

// ---------------- main fused kernel ----------------
// 1 block = 1 window. 512 threads = 8 waves. 65.5 KB LDS -> 2 blocks/CU.
// Per head: X = {out += P_{h-1} EN'_{h-1} ; Z^T = G Ê^T (norm diags) ; T1 = Ê M̂^T}
//           Y = {S = T1 Ê^T -> P ; EN'_h = Ê NT_h^T (transposed store)}
__global__ __launch_bounds__(512, 4) void k_msa(
    const float* __restrict__ E,
    const u16* __restrict__ BigB, const u16* __restrict__ NT,
    const float* __restrict__ biasT, const float* __restrict__ temp,
    const float* __restrict__ cq4, const float* __restrict__ Ab,
    float* __restrict__ out) {
  __shared__ __align__(16) u16 sE[64 * 168];    // Ê: cols 0..127=E, 128=1, 129..159=0
  __shared__ __align__(16) u16 sT1[64 * 136];   // T1 = Ê M̂^T
  __shared__ __align__(16) u16 sP[64 * 72];     // P (bf16)
  __shared__ __align__(16) u16 sENT[128 * 72];  // EN'^T [c][j]
  __shared__ float sDq[64], sDk[64];            // ||q||^2-cq, ||k||^2

  const int tid = threadIdx.x;
  const int wid = tid >> 6;
  const int lane = tid & 63;
  const int l15 = lane & 15;
  const int lk4 = (lane >> 4) << 2;
  const int lk8 = (lane >> 4) << 3;
  const int b = blockIdx.x;
  const float* Eb = E + (size_t)b * 8192;
  const int onc = wid << 4;                     // this wave's output/EN col strip

  // ---- stage Ê
  {
    const float4* E4 = (const float4*)Eb;
    #pragma unroll
    for (int it = 0; it < 4; ++it) {
      int i = tid + it * 512;                   // 2048 float4
      float4 v = E4[i];
      int row = i >> 5, c = (i & 31) << 2;
      s16x4 u;
      u[0] = (short)f2bf(v.x); u[1] = (short)f2bf(v.y);
      u[2] = (short)f2bf(v.z); u[3] = (short)f2bf(v.w);
      *(s16x4*)&sE[row * 168 + c] = u;
    }
    {
      int row = tid >> 3, p = tid & 7;          // aug cols 128..159
      s16x4 zz = {0, 0, 0, 0};
      if (p == 0) zz[0] = (short)0x3F80;        // bf16(1.0)
      *(s16x4*)&sE[row * 168 + 128 + p * 4] = zz;
    }
  }
  __syncthreads();

  const f32x4 zf4 = {0.f, 0.f, 0.f, 0.f};
  f32x4 oacc[4];
  #pragma unroll
  for (int m = 0; m < 4; ++m) oacc[m] = zf4;

  for (int h = 0; h < 4; ++h) {
    // ================= X phase =================
    if (h > 0) {
      // out += P_{h-1} @ EN'_{h-1}   (K = 64)
      #pragma unroll
      for (int ks = 0; ks < 2; ++ks) {
        const int koff = ks * 32 + lk8;
        bf16x8 bw = *(const bf16x8*)&sENT[(onc + l15) * 72 + koff];
        #pragma unroll
        for (int m = 0; m < 4; ++m) {
          bf16x8 a = *(const bf16x8*)&sP[(m * 16 + l15) * 72 + koff];
          oacc[m] = MFMA(a, bw, oacc[m]);
        }
      }
    }
    // Z^T = Ĝ @ Ê^T : waves 0-3 -> Gq (i-tile wid), waves 4-7 -> Gk
    {
      const int zt = (wid < 4) ? 1 : 2;
      const int nt = wid & 3;
      f32x4 zacc[8];
      #pragma unroll
      for (int m = 0; m < 8; ++m) zacc[m] = zf4;
      #pragma unroll
      for (int ks = 0; ks < 5; ++ks) {
        const int koff = ks * 32 + lk8;
        bf16x8 bw = *(const bf16x8*)&sE[(nt * 16 + l15) * 168 + koff];
        #pragma unroll
        for (int m = 0; m < 8; ++m) {
          bf16x8 a = *(const bf16x8*)&BigB[(size_t)(h * 384 + zt * 128 + m * 16 + l15) * 160 + koff];
          zacc[m] = MFMA(a, bw, zacc[m]);
        }
      }
      // diag: D[i] = sum_f Z^T[f][i] * E[i][f]  (f in-lane, 2 shuffles cross-group)
      const int i = nt * 16 + l15;
      float p = 0.f;
      #pragma unroll
      for (int m = 0; m < 8; ++m) {
        s16x4 ev = *(const s16x4*)&sE[i * 168 + m * 16 + lk4];
        #pragma unroll
        for (int r = 0; r < 4; ++r)
          p = fmaf(zacc[m][r], bf2f((u16)ev[r]), p);
      }
      p += __shfl_xor(p, 16);
      p += __shfl_xor(p, 32);
      if (lane < 16) {
        if (wid < 4) sDq[i] = p;
        else         sDk[i] = p;
      }
    }
    // T1 = Ê @ M̂^T (64 x 128, K=160), col strip per wave
    {
      f32x4 tacc[4];
      #pragma unroll
      for (int m = 0; m < 4; ++m) tacc[m] = zf4;
      #pragma unroll
      for (int ks = 0; ks < 5; ++ks) {
        const int koff = ks * 32 + lk8;
        bf16x8 bw = *(const bf16x8*)&BigB[(size_t)(h * 384 + onc + l15) * 160 + koff];
        #pragma unroll
        for (int m = 0; m < 4; ++m) {
          bf16x8 a = *(const bf16x8*)&sE[(m * 16 + l15) * 168 + koff];
          tacc[m] = MFMA(a, bw, tacc[m]);
        }
      }
      const int col = onc + l15;
      #pragma unroll
      for (int m = 0; m < 4; ++m)
        #pragma unroll
        for (int r = 0; r < 4; ++r)
          sT1[(m * 16 + lk4 + r) * 136 + col] = f2bf(tacc[m][r]);
    }
    __syncthreads();
    // ================= Y phase =================
    {
      // S = T1 @ Ê^T (K=128): 2 tiles per wave
      const int mt = wid >> 1, j0 = (wid & 1) * 32;
      f32x4 acc[2] = {zf4, zf4};
      #pragma unroll
      for (int ks = 0; ks < 4; ++ks) {
        const int koff = ks * 32 + lk8;
        bf16x8 a = *(const bf16x8*)&sT1[(mt * 16 + l15) * 136 + koff];
        #pragma unroll
        for (int n = 0; n < 2; ++n) {
          bf16x8 bw = *(const bf16x8*)&sE[(j0 + n * 16 + l15) * 168 + koff];
          acc[n] = MFMA(a, bw, acc[n]);
        }
      }
      // EN'_h = Ê @ NT_h^T (K=160), store transposed
      f32x4 eacc[4];
      #pragma unroll
      for (int m = 0; m < 4; ++m) eacc[m] = zf4;
      #pragma unroll
      for (int ks = 0; ks < 5; ++ks) {
        const int koff = ks * 32 + lk8;
        bf16x8 bw = *(const bf16x8*)&NT[(size_t)(h * 128 + onc + l15) * 160 + koff];
        #pragma unroll
        for (int m = 0; m < 4; ++m) {
          bf16x8 a = *(const bf16x8*)&sE[(m * 16 + l15) * 168 + koff];
          eacc[m] = MFMA(a, bw, eacc[m]);
        }
      }
      // P epilogue
      const float th = temp[h], cqh = cq4[h];
      const int i0 = mt * 16 + lk4;
      float qs[4];
      #pragma unroll
      for (int r = 0; r < 4; ++r) {
        float dq = fmaxf(sDq[i0 + r] + cqh, 0.f);
        qs[r] = th / fmaxf(sqrtf(dq), 1e-12f);
      }
      #pragma unroll
      for (int n = 0; n < 2; ++n) {
        const int j = j0 + n * 16 + l15;
        const float ki = 1.f / fmaxf(sqrtf(fmaxf(sDk[j], 0.f)), 1e-12f);
        const f32x4 bb = *(const f32x4*)&biasT[h * 4096 + j * 64 + i0];
        #pragma unroll
        for (int r = 0; r < 4; ++r)
          sP[(i0 + r) * 72 + j] = f2bf(fmaf(acc[n][r] * qs[r], ki, bb[r]));
      }
      // EN' epilogue: transposed store sENT[c][j]
      const int c = onc + l15;
      #pragma unroll
      for (int m = 0; m < 4; ++m) {
        s16x4 u;
        u[0] = (short)f2bf(eacc[m][0]); u[1] = (short)f2bf(eacc[m][1]);
        u[2] = (short)f2bf(eacc[m][2]); u[3] = (short)f2bf(eacc[m][3]);
        *(s16x4*)&sENT[c * 72 + m * 16 + lk4] = u;
      }
    }
    __syncthreads();
  }

  // ---- tail: out += P_3 @ EN'_3 ; + bias ; f32 store
  {
    #pragma unroll
    for (int ks = 0; ks < 2; ++ks) {
      const int koff = ks * 32 + lk8;
      bf16x8 bw = *(const bf16x8*)&sENT[(onc + l15) * 72 + koff];
      #pragma unroll
      for (int m = 0; m < 4; ++m) {
        bf16x8 a = *(const bf16x8*)&sP[(m * 16 + l15) * 72 + koff];
        oacc[m] = MFMA(a, bw, oacc[m]);
      }
    }
    float* ob = out + (size_t)b * 8192;
    const float bv = Ab[onc + l15];
    #pragma unroll
    for (int m = 0; m < 4; ++m)
      #pragma unroll
      for (int r = 0; r < 4; ++r)
        ob[(m * 16 + lk4 + r) * 128 + onc + l15] = oacc[m][r] + bv;
  }
}

// ---------------- host ----------------
extern "C" void kernel_launch(void* const* d_in, const int* in_sizes, int n_in,
                              void* d_out, int out_size, void* d_ws, size_t ws_size,
                              hipStream_t stream) {
  const float* E    = (const float*)d_in[0];
  const float* rpos = (const float*)d_in[1];
  const int*   ridx = (const int*)d_in[2];
  const float* Wq   = (const float*)d_in[3];
  const float* Qb   = (const float*)d_in[4];
  const float* Wk   = (const float*)d_in[5];
  const float* Wv   = (const float*)d_in[6];
  const float* Vb   = (const float*)d_in[7];
  const float* Wa   = (const float*)d_in[8];
  const float* Ab   = (const float*)d_in[9];
  const float* w1   = (const float*)d_in[10];
  const float* b1   = (const float*)d_in[11];
  const float* w2   = (const float*)d_in[12];
  const float* ls   = (const float*)d_in[13];

  char* ws = (char*)d_ws;
  u16* BigB    = (u16*)(ws + 0);         // 4*384*160*2 = 491520
  u16* NT      = (u16*)(ws + 491520);    // 4*128*160*2 = 163840
  float* biasT = (float*)(ws + 655360);  // 65536
  float* temp  = (float*)(ws + 720896);  // 64
  float* cq4   = (float*)(ws + 720960);  // 64

  k_gram<<<16, 256, 0, stream>>>(Wq, Wk, Wv, Wa, Qb, Vb, BigB, NT, cq4);
  k_tb<<<1, 256, 0, stream>>>(rpos, w1, b1, w2, ls, ridx, biasT, temp);
  k_msa<<<1024, 512, 0, stream>>>(E, BigB, NT, biasT, temp, cq4, Ab,
                                  (float*)d_out);
}

// Round 4
// 227.436 us; speedup vs baseline: 1.4575x; 1.4575x over previous
//
#include <hip/hip_runtime.h>
#include <hip/hip_bf16.h>
#include <cstdint>

typedef uint16_t u16;
typedef __attribute__((ext_vector_type(8))) __bf16 bf16x8;
typedef __attribute__((ext_vector_type(4))) short s16x4;
typedef __attribute__((ext_vector_type(8))) short s16x8;
typedef __attribute__((ext_vector_type(4))) float f32x4;

#define MFMA(a, b, c) __builtin_amdgcn_mfma_f32_16x16x32_bf16((a), (b), (c), 0, 0, 0)
#define LOG100 4.6051701859880914f

__device__ __forceinline__ u16 f2bf(float f) {
  union { float f; uint32_t u; } v; v.f = f;
  uint32_t u = v.u;
  return (u16)((u + 0x7FFFu + ((u >> 16) & 1u)) >> 16);
}
__device__ __forceinline__ float bf2f(u16 s) {
  union { uint32_t u; float f; } v; v.u = ((uint32_t)s) << 16;
  return v.f;
}

union U8 { s16x8 s; bf16x8 b; };

__device__ __forceinline__ bf16x8 ld_bf8(const float* __restrict__ p) {
  float4 v0 = *(const float4*)p;
  float4 v1 = *(const float4*)(p + 4);
  U8 u;
  u.s[0] = (short)f2bf(v0.x); u.s[1] = (short)f2bf(v0.y);
  u.s[2] = (short)f2bf(v0.z); u.s[3] = (short)f2bf(v0.w);
  u.s[4] = (short)f2bf(v1.x); u.s[5] = (short)f2bf(v1.y);
  u.s[6] = (short)f2bf(v1.z); u.s[7] = (short)f2bf(v1.w);
  return u.b;
}
__device__ __forceinline__ bf16x8 ld_bf8_s128(const float* __restrict__ p) {
  U8 u;
  #pragma unroll
  for (int e = 0; e < 8; ++e) u.s[e] = (short)f2bf(p[(size_t)e * 128]);
  return u.b;
}
__device__ __forceinline__ bf16x8 zero_bf8() {
  U8 u;
  #pragma unroll
  for (int e = 0; e < 8; ++e) u.s[e] = 0;
  return u.b;
}

// ---------------- prep kernel: 17 blocks ----------------
// blocks 0..15 = (h, t):
//  t=0: BigB_M  rows l (Wk dim), cols e (Wq dim): M[l,e] = Wq[e].Wk[l]
//  t=1: BigB_Gq rows l, cols e: Wq[l].Wq[e]; + virtual qb row -> augGq[e] = 2 Wq[e].qb
//  t=2: BigB_Gk rows l, cols e: Wk[l].Wk[e]; + virtual qb row -> augM[e]  = Wk[e].qb
//  t=3: NT rows c, cols a: N[a,c] = Wv[a].Wa[:,c]; + virtual vb A-row -> w4[c] = vb.Wa[:,c]
// block 16: bias table (bf16) + temp + cq4
__global__ __launch_bounds__(256) void k_prep(
    const float* __restrict__ Wq, const float* __restrict__ Wk,
    const float* __restrict__ Wv, const float* __restrict__ Wa,
    const float* __restrict__ Qb, const float* __restrict__ Vb,
    const float* __restrict__ rpos, const float* __restrict__ w1,
    const float* __restrict__ b1, const float* __restrict__ w2,
    const float* __restrict__ ls, const int* __restrict__ ridx,
    u16* __restrict__ BigB, u16* __restrict__ NT, u16* __restrict__ biasTb,
    float* __restrict__ augM, float* __restrict__ augGq,
    float* __restrict__ w4, float* __restrict__ cq4, float* __restrict__ temp) {
  __shared__ float tbl[225][4];
  const int bid = blockIdx.x;
  const int tid = threadIdx.x;

  if (bid == 16) {
    if (tid < 225) {
      float x0 = rpos[tid * 2 + 0], x1 = rpos[tid * 2 + 1];
      float a0 = 0.f, a1 = 0.f, a2 = 0.f, a3 = 0.f;
      for (int c = 0; c < 512; ++c) {
        float hv = fmaxf(fmaf(x0, w1[c], fmaf(x1, w1[512 + c], b1[c])), 0.f);
        a0 = fmaf(hv, w2[c * 4 + 0], a0);
        a1 = fmaf(hv, w2[c * 4 + 1], a1);
        a2 = fmaf(hv, w2[c * 4 + 2], a2);
        a3 = fmaf(hv, w2[c * 4 + 3], a3);
      }
      tbl[tid][0] = a0; tbl[tid][1] = a1; tbl[tid][2] = a2; tbl[tid][3] = a3;
    }
    if (tid < 4) temp[tid] = expf(fminf(ls[tid], LOG100));
    {
      int hh = tid >> 6, l = tid & 63;
      float s = 0.f;
      #pragma unroll
      for (int p = 0; p < 6; ++p) {
        float v = Qb[hh * 384 + l * 6 + p];
        s = fmaf(v, v, s);
      }
      s += __shfl_xor(s, 1); s += __shfl_xor(s, 2); s += __shfl_xor(s, 4);
      s += __shfl_xor(s, 8); s += __shfl_xor(s, 16); s += __shfl_xor(s, 32);
      if (l == 0) cq4[hh] = s;
    }
    __syncthreads();
    for (int it = 0; it < 64; ++it) {
      int gid = it * 256 + tid;
      int h = gid >> 12;
      int rem = gid & 4095;
      int q = rem >> 6, p = rem & 63;
      int ii = ((p >> 3) << 3) + (q >> 3);
      int jj = ((p & 7) << 3) + (q & 7);
      float v = tbl[ridx[ii * 64 + jj]][h];
      biasTb[gid] = f2bf(16.f / (1.f + expf(-v)));
    }
    return;
  }

  const int h = bid >> 2, t = bid & 3;
  const int wid = tid >> 6, lane = tid & 63;
  const int l15 = lane & 15, lk4 = (lane >> 4) << 2, lk8 = (lane >> 4) << 3;
  const f32x4 zf4 = {0.f, 0.f, 0.f, 0.f};

  f32x4 acc[2][8];
  #pragma unroll
  for (int mm = 0; mm < 2; ++mm)
    #pragma unroll
    for (int nn = 0; nn < 8; ++nn) acc[mm][nn] = zf4;

  if (t < 3) {
    const float* A = (t == 2) ? Wk : Wq;
    const float* B = (t == 0) ? Wk : ((t == 1) ? Wq : Wk);
    f32x4 accq[2] = {zf4, zf4};
    for (int ks = 0; ks < 12; ++ks) {
      const int koff = h * 384 + ks * 32 + lk8;
      bf16x8 a[2], bw[8];
      #pragma unroll
      for (int mm = 0; mm < 2; ++mm)
        a[mm] = ld_bf8(&A[(size_t)(wid * 32 + mm * 16 + l15) * 1536 + koff]);
      #pragma unroll
      for (int nn = 0; nn < 8; ++nn)
        bw[nn] = ld_bf8(&B[(size_t)(nn * 16 + l15) * 1536 + koff]);
      #pragma unroll
      for (int nn = 0; nn < 8; ++nn)
        #pragma unroll
        for (int mm = 0; mm < 2; ++mm)
          acc[mm][nn] = MFMA(a[mm], bw[nn], acc[mm][nn]);
      if (t >= 1) {
        bf16x8 bq = (l15 == 0) ? ld_bf8(&Qb[koff]) : zero_bf8();
        #pragma unroll
        for (int mm = 0; mm < 2; ++mm) accq[mm] = MFMA(a[mm], bq, accq[mm]);
      }
    }
    u16* dst = BigB + (size_t)((h * 3 + t) * 128) * 128;
    #pragma unroll
    for (int mm = 0; mm < 2; ++mm) {
      const int k0 = wid * 32 + mm * 16 + lk4;
      #pragma unroll
      for (int nn = 0; nn < 8; ++nn) {
        s16x4 u;
        u[0] = (short)f2bf(acc[mm][nn][0]); u[1] = (short)f2bf(acc[mm][nn][1]);
        u[2] = (short)f2bf(acc[mm][nn][2]); u[3] = (short)f2bf(acc[mm][nn][3]);
        *(s16x4*)&dst[(nn * 16 + l15) * 128 + k0] = u;
      }
    }
    if (t >= 1 && l15 == 0) {
      float* tgt = (t == 1) ? augGq : augM;
      const float sc = (t == 1) ? 2.f : 1.f;
      #pragma unroll
      for (int mm = 0; mm < 2; ++mm)
        #pragma unroll
        for (int r = 0; r < 4; ++r)
          tgt[h * 128 + wid * 32 + mm * 16 + lk4 + r] = sc * accq[mm][r];
    }
  } else {
    f32x4 accv[8];
    #pragma unroll
    for (int nn = 0; nn < 8; ++nn) accv[nn] = zf4;
    for (int ks = 0; ks < 12; ++ks) {
      const int koff = h * 384 + ks * 32 + lk8;
      bf16x8 a[2], bw[8];
      #pragma unroll
      for (int mm = 0; mm < 2; ++mm)
        a[mm] = ld_bf8(&Wv[(size_t)(wid * 32 + mm * 16 + l15) * 1536 + koff]);
      #pragma unroll
      for (int nn = 0; nn < 8; ++nn)
        bw[nn] = ld_bf8_s128(&Wa[(size_t)koff * 128 + nn * 16 + l15]);
      #pragma unroll
      for (int nn = 0; nn < 8; ++nn)
        #pragma unroll
        for (int mm = 0; mm < 2; ++mm)
          acc[mm][nn] = MFMA(a[mm], bw[nn], acc[mm][nn]);
      if (wid == 0) {
        bf16x8 av = (l15 == 0) ? ld_bf8(&Vb[koff]) : zero_bf8();
        #pragma unroll
        for (int nn = 0; nn < 8; ++nn) accv[nn] = MFMA(av, bw[nn], accv[nn]);
      }
    }
    u16* dst = NT + (size_t)(h * 128) * 128;
    #pragma unroll
    for (int mm = 0; mm < 2; ++mm) {
      const int k0 = wid * 32 + mm * 16 + lk4;
      #pragma unroll
      for (int nn = 0; nn < 8; ++nn) {
        s16x4 u;
        u[0] = (short)f2bf(acc[mm][nn][0]); u[1] = (short)f2bf(acc[mm][nn][1]);
        u[2] = (short)f2bf(acc[mm][nn][2]); u[3] = (short)f2bf(acc[mm][nn][3]);
        *(s16x4*)&dst[(nn * 16 + l15) * 128 + k0] = u;
      }
    }
    if (wid == 0 && lane < 16) {
      #pragma unroll
      for (int nn = 0; nn < 8; ++nn)
        w4[h * 128 + nn * 16 + lane] = accv[nn][0];
    }
  }
}

// ---------------- main fused kernel ----------------
// 1 block = 1 window. 512 threads = 8 waves. ~64.5 KB LDS -> 2 blocks/CU.
// X = {out += P_{h-1} EN_{h-1}; Z = G E^T (diag partials); T1 = E M^T + augM}
// Y = {S = T1 E^T -> P; EN = E N + w4 (transposed store)}
__global__ __launch_bounds__(512, 4) void k_msa(
    const float* __restrict__ E,
    const u16* __restrict__ BigB, const u16* __restrict__ NT,
    const u16* __restrict__ biasTb,
    const float* __restrict__ augM, const float* __restrict__ augGq,
    const float* __restrict__ w4, const float* __restrict__ cq4,
    const float* __restrict__ temp, const float* __restrict__ Ab,
    float* __restrict__ out) {
  __shared__ __align__(16) u16 sE[64 * 136];
  __shared__ __align__(16) u16 sT1[64 * 136];
  __shared__ __align__(16) u16 sP[64 * 72];
  __shared__ __align__(16) u16 sENT[128 * 72];
  __shared__ float sDqp[4][64];
  __shared__ float sDkp[4][64];

  const int tid = threadIdx.x;
  const int wid = tid >> 6;
  const int lane = tid & 63;
  const int l15 = lane & 15;
  const int lk4 = (lane >> 4) << 2;
  const int lk8 = (lane >> 4) << 3;
  const int b = blockIdx.x;
  const int mt = wid >> 1;        // PV/S row tile
  const int ch = wid & 1;         // PV col half
  const int j0 = ch * 32;         // S col base
  const int onc = wid << 4;       // T1/EN col strip

  // ---- stage E (f32 -> bf16, non-temporal)
  {
    typedef __attribute__((ext_vector_type(4))) float f4;
    const f4* E4 = (const f4*)(E + (size_t)b * 8192);
    #pragma unroll
    for (int it = 0; it < 4; ++it) {
      int i = tid + it * 512;
      f4 v = __builtin_nontemporal_load(&E4[i]);
      int row = i >> 5, c = (i & 31) << 2;
      s16x4 u;
      u[0] = (short)f2bf(v[0]); u[1] = (short)f2bf(v[1]);
      u[2] = (short)f2bf(v[2]); u[3] = (short)f2bf(v[3]);
      *(s16x4*)&sE[row * 136 + c] = u;
    }
  }
  __syncthreads();

  const f32x4 zf4 = {0.f, 0.f, 0.f, 0.f};
  f32x4 oacc[4];
  #pragma unroll
  for (int n = 0; n < 4; ++n) oacc[n] = zf4;

  for (int h = 0; h < 4; ++h) {
    // ================= X phase =================
    if (h > 0) {
      #pragma unroll
      for (int ks = 0; ks < 2; ++ks) {
        const int koff = ks * 32 + lk8;
        bf16x8 a = *(const bf16x8*)&sP[(mt * 16 + l15) * 72 + koff];
        #pragma unroll
        for (int n = 0; n < 4; ++n) {
          bf16x8 bw = *(const bf16x8*)&sENT[(ch * 64 + n * 16 + l15) * 72 + koff];
          oacc[n] = MFMA(a, bw, oacc[n]);
        }
      }
    }
    // Z = G E^T; wave owns 32 G rows x all 64 cols
    {
      const int zt = (wid < 4) ? 1 : 2;
      const int rw = (wid & 3) * 32;
      const u16* G = BigB + (size_t)((h * 3 + zt) * 128 + rw) * 128;
      f32x4 z[2][4];
      #pragma unroll
      for (int mm = 0; mm < 2; ++mm)
        #pragma unroll
        for (int n = 0; n < 4; ++n) z[mm][n] = zf4;
      #pragma unroll
      for (int ks = 0; ks < 4; ++ks) {
        const int koff = ks * 32 + lk8;
        bf16x8 a0 = *(const bf16x8*)&G[(l15) * 128 + koff];
        bf16x8 a1 = *(const bf16x8*)&G[(16 + l15) * 128 + koff];
        #pragma unroll
        for (int n = 0; n < 4; ++n) {
          bf16x8 bw = *(const bf16x8*)&sE[(n * 16 + l15) * 136 + koff];
          z[0][n] = MFMA(a0, bw, z[0][n]);
          z[1][n] = MFMA(a1, bw, z[1][n]);
        }
      }
      float aq[2][4];
      #pragma unroll
      for (int mm = 0; mm < 2; ++mm)
        #pragma unroll
        for (int r = 0; r < 4; ++r)
          aq[mm][r] = (wid < 4) ? augGq[h * 128 + rw + mm * 16 + lk4 + r] : 0.f;
      #pragma unroll
      for (int n = 0; n < 4; ++n) {
        const int j = n * 16 + l15;
        float p = 0.f;
        #pragma unroll
        for (int mm = 0; mm < 2; ++mm)
          #pragma unroll
          for (int r = 0; r < 4; ++r)
            p = fmaf(z[mm][n][r] + aq[mm][r],
                     bf2f(sE[j * 136 + rw + mm * 16 + lk4 + r]), p);
        p += __shfl_xor(p, 16);
        p += __shfl_xor(p, 32);
        if (lane < 16) {
          if (wid < 4) sDqp[wid & 3][j] = p;
          else         sDkp[wid & 3][j] = p;
        }
      }
    }
    // T1 = E M^T + augM ; col strip per wave
    {
      const u16* M = BigB + (size_t)(h * 3 * 128) * 128;
      f32x4 t1[4];
      #pragma unroll
      for (int m = 0; m < 4; ++m) t1[m] = zf4;
      #pragma unroll
      for (int ks = 0; ks < 4; ++ks) {
        const int koff = ks * 32 + lk8;
        bf16x8 bw = *(const bf16x8*)&M[(onc + l15) * 128 + koff];
        #pragma unroll
        for (int m = 0; m < 4; ++m) {
          bf16x8 a = *(const bf16x8*)&sE[(m * 16 + l15) * 136 + koff];
          t1[m] = MFMA(a, bw, t1[m]);
        }
      }
      const float ta = augM[h * 128 + onc + l15];
      const int col = onc + l15;
      #pragma unroll
      for (int m = 0; m < 4; ++m)
        #pragma unroll
        for (int r = 0; r < 4; ++r)
          sT1[(m * 16 + lk4 + r) * 136 + col] = f2bf(t1[m][r] + ta);
    }
    __syncthreads();
    // ================= Y phase =================
    {
      // S = T1 E^T (K=128)
      f32x4 s2[2] = {zf4, zf4};
      #pragma unroll
      for (int ks = 0; ks < 4; ++ks) {
        const int koff = ks * 32 + lk8;
        bf16x8 a = *(const bf16x8*)&sT1[(mt * 16 + l15) * 136 + koff];
        #pragma unroll
        for (int n = 0; n < 2; ++n) {
          bf16x8 bw = *(const bf16x8*)&sE[(j0 + n * 16 + l15) * 136 + koff];
          s2[n] = MFMA(a, bw, s2[n]);
        }
      }
      // EN = E N + w4 (K=128)
      const u16* Nt = NT + (size_t)(h * 128) * 128;
      f32x4 en[4];
      #pragma unroll
      for (int m = 0; m < 4; ++m) en[m] = zf4;
      #pragma unroll
      for (int ks = 0; ks < 4; ++ks) {
        const int koff = ks * 32 + lk8;
        bf16x8 bw = *(const bf16x8*)&Nt[(onc + l15) * 128 + koff];
        #pragma unroll
        for (int m = 0; m < 4; ++m) {
          bf16x8 a = *(const bf16x8*)&sE[(m * 16 + l15) * 136 + koff];
          en[m] = MFMA(a, bw, en[m]);
        }
      }
      // P epilogue
      const float th = temp[h], cqh = cq4[h];
      const int i0 = mt * 16 + lk4;
      f32x4 dq = *(const f32x4*)&sDqp[0][i0];
      dq += *(const f32x4*)&sDqp[1][i0];
      dq += *(const f32x4*)&sDqp[2][i0];
      dq += *(const f32x4*)&sDqp[3][i0];
      float qs[4];
      #pragma unroll
      for (int r = 0; r < 4; ++r)
        qs[r] = th / fmaxf(sqrtf(fmaxf(dq[r] + cqh, 0.f)), 1e-12f);
      #pragma unroll
      for (int n = 0; n < 2; ++n) {
        const int j = j0 + n * 16 + l15;
        const float dk = sDkp[0][j] + sDkp[1][j] + sDkp[2][j] + sDkp[3][j];
        const float ki = 1.f / fmaxf(sqrtf(fmaxf(dk, 0.f)), 1e-12f);
        s16x4 bb = *(const s16x4*)&biasTb[h * 4096 + j * 64 + i0];
        #pragma unroll
        for (int r = 0; r < 4; ++r)
          sP[(i0 + r) * 72 + j] = f2bf(fmaf(s2[n][r] * qs[r], ki, bf2f((u16)bb[r])));
      }
      // EN epilogue: transposed store
      const float wc = w4[h * 128 + onc + l15];
      #pragma unroll
      for (int m = 0; m < 4; ++m) {
        s16x4 u;
        u[0] = (short)f2bf(en[m][0] + wc); u[1] = (short)f2bf(en[m][1] + wc);
        u[2] = (short)f2bf(en[m][2] + wc); u[3] = (short)f2bf(en[m][3] + wc);
        *(s16x4*)&sENT[(onc + l15) * 72 + m * 16 + lk4] = u;
      }
    }
    __syncthreads();
  }

  // ---- tail: out += P_3 EN_3 ; + bias ; non-temporal f32 store
  {
    #pragma unroll
    for (int ks = 0; ks < 2; ++ks) {
      const int koff = ks * 32 + lk8;
      bf16x8 a = *(const bf16x8*)&sP[(mt * 16 + l15) * 72 + koff];
      #pragma unroll
      for (int n = 0; n < 4; ++n) {
        bf16x8 bw = *(const bf16x8*)&sENT[(ch * 64 + n * 16 + l15) * 72 + koff];
        oacc[n] = MFMA(a, bw, oacc[n]);
      }
    }
    float* ob = out + (size_t)b * 8192;
    #pragma unroll
    for (int n = 0; n < 4; ++n) {
      const int col = ch * 64 + n * 16 + l15;
      const float bv = Ab[col];
      #pragma unroll
      for (int r = 0; r < 4; ++r)
        __builtin_nontemporal_store(oacc[n][r] + bv,
                                    &ob[(mt * 16 + lk4 + r) * 128 + col]);
    }
  }
}

// ---------------- host ----------------
extern "C" void kernel_launch(void* const* d_in, const int* in_sizes, int n_in,
                              void* d_out, int out_size, void* d_ws, size_t ws_size,
                              hipStream_t stream) {
  const float* E    = (const float*)d_in[0];
  const float* rpos = (const float*)d_in[1];
  const int*   ridx = (const int*)d_in[2];
  const float* Wq   = (const float*)d_in[3];
  const float* Qb   = (const float*)d_in[4];
  const float* Wk   = (const float*)d_in[5];
  const float* Wv   = (const float*)d_in[6];
  const float* Vb   = (const float*)d_in[7];
  const float* Wa   = (const float*)d_in[8];
  const float* Ab   = (const float*)d_in[9];
  const float* w1   = (const float*)d_in[10];
  const float* b1   = (const float*)d_in[11];
  const float* w2   = (const float*)d_in[12];
  const float* ls   = (const float*)d_in[13];

  char* ws = (char*)d_ws;
  u16* BigB    = (u16*)(ws + 0);         // 4*3*128*128*2 = 393216
  u16* NT      = (u16*)(ws + 393216);    // 4*128*128*2   = 131072
  u16* biasTb  = (u16*)(ws + 524288);    // 16384*2       = 32768
  float* augM  = (float*)(ws + 557056);  // 512*4
  float* augGq = (float*)(ws + 559104);  // 512*4
  float* w4    = (float*)(ws + 561152);  // 512*4
  float* cq4   = (float*)(ws + 563200);  // 16
  float* temp  = (float*)(ws + 563264);  // 16

  k_prep<<<17, 256, 0, stream>>>(Wq, Wk, Wv, Wa, Qb, Vb, rpos, w1, b1, w2,
                                 ls, ridx, BigB, NT, biasTb, augM, augGq,
                                 w4, cq4, temp);
  k_msa<<<1024, 512, 0, stream>>>(E, BigB, NT, biasTb, augM, augGq, w4,
                                  cq4, temp, Ab, (float*)d_out);
}

// Round 5
// 218.152 us; speedup vs baseline: 1.5195x; 1.0426x over previous
//
#include <hip/hip_runtime.h>
#include <hip/hip_bf16.h>
#include <cstdint>

typedef uint16_t u16;
typedef __attribute__((ext_vector_type(8))) __bf16 bf16x8;
typedef __attribute__((ext_vector_type(4))) short s16x4;
typedef __attribute__((ext_vector_type(8))) short s16x8;
typedef __attribute__((ext_vector_type(4))) float f32x4;

#define MFMA(a, b, c) __builtin_amdgcn_mfma_f32_16x16x32_bf16((a), (b), (c), 0, 0, 0)
#define LOG100 4.6051701859880914f

__device__ __forceinline__ u16 f2bf(float f) {
  union { float f; uint32_t u; } v; v.f = f;
  uint32_t u = v.u;
  return (u16)((u + 0x7FFFu + ((u >> 16) & 1u)) >> 16);
}
__device__ __forceinline__ float bf2f(u16 s) {
  union { uint32_t u; float f; } v; v.u = ((uint32_t)s) << 16;
  return v.f;
}

union U8 { s16x8 s; bf16x8 b; };

__device__ __forceinline__ bf16x8 ld_bf8(const float* __restrict__ p) {
  float4 v0 = *(const float4*)p;
  float4 v1 = *(const float4*)(p + 4);
  U8 u;
  u.s[0] = (short)f2bf(v0.x); u.s[1] = (short)f2bf(v0.y);
  u.s[2] = (short)f2bf(v0.z); u.s[3] = (short)f2bf(v0.w);
  u.s[4] = (short)f2bf(v1.x); u.s[5] = (short)f2bf(v1.y);
  u.s[6] = (short)f2bf(v1.z); u.s[7] = (short)f2bf(v1.w);
  return u.b;
}
__device__ __forceinline__ bf16x8 zero_bf8() {
  U8 u;
  #pragma unroll
  for (int e = 0; e < 8; ++e) u.s[e] = 0;
  return u.b;
}

// ---------------- prep kernel: 17 blocks ----------------
// blocks 0..15 = (h, t):
//  t=0: BigB_M  rows l (Wk dim), cols e: M[l,e] = Wq[e].Wk[l]
//  t=1: BigB_Gq rows l, cols e: Wq[l].Wq[e]; virtual qb B-row -> augGq[e] = 2 Wq[e].qb
//  t=2: BigB_Gk rows l, cols e: Wk[l].Wk[e]; virtual qb B-row -> augM[e]  = Wk[e].qb
//  t=3: NT rows c, cols e: N[e,c] = sum_a Wv[e][ha] Wa[ha][c]; virtual vb A-row -> w4[c]
// block 16: bias table (bf16) + temp + cq4
__global__ __launch_bounds__(256) void k_prep(
    const float* __restrict__ Wq, const float* __restrict__ Wk,
    const float* __restrict__ Wv, const float* __restrict__ Wa,
    const float* __restrict__ Qb, const float* __restrict__ Vb,
    const float* __restrict__ rpos, const float* __restrict__ w1,
    const float* __restrict__ b1, const float* __restrict__ w2,
    const float* __restrict__ ls, const int* __restrict__ ridx,
    u16* __restrict__ BigB, u16* __restrict__ NT, u16* __restrict__ biasTb,
    float* __restrict__ augM, float* __restrict__ augGq,
    float* __restrict__ w4, float* __restrict__ cq4, float* __restrict__ temp) {
  __shared__ float tbl[225][4];
  __shared__ __align__(16) u16 sWaT[128 * 200];   // Wa^T chunk [c][a'], a' < 192
  const int bid = blockIdx.x;
  const int tid = threadIdx.x;

  if (bid == 16) {
    if (tid < 225) {
      float x0 = rpos[tid * 2 + 0], x1 = rpos[tid * 2 + 1];
      float a0 = 0.f, a1 = 0.f, a2 = 0.f, a3 = 0.f;
      for (int c = 0; c < 512; ++c) {
        float hv = fmaxf(fmaf(x0, w1[c], fmaf(x1, w1[512 + c], b1[c])), 0.f);
        a0 = fmaf(hv, w2[c * 4 + 0], a0);
        a1 = fmaf(hv, w2[c * 4 + 1], a1);
        a2 = fmaf(hv, w2[c * 4 + 2], a2);
        a3 = fmaf(hv, w2[c * 4 + 3], a3);
      }
      tbl[tid][0] = a0; tbl[tid][1] = a1; tbl[tid][2] = a2; tbl[tid][3] = a3;
    }
    if (tid < 4) temp[tid] = expf(fminf(ls[tid], LOG100));
    {
      int hh = tid >> 6, l = tid & 63;
      float s = 0.f;
      #pragma unroll
      for (int p = 0; p < 6; ++p) {
        float v = Qb[hh * 384 + l * 6 + p];
        s = fmaf(v, v, s);
      }
      s += __shfl_xor(s, 1); s += __shfl_xor(s, 2); s += __shfl_xor(s, 4);
      s += __shfl_xor(s, 8); s += __shfl_xor(s, 16); s += __shfl_xor(s, 32);
      if (l == 0) cq4[hh] = s;
    }
    __syncthreads();
    for (int it = 0; it < 64; ++it) {
      int gid = it * 256 + tid;
      int h = gid >> 12;
      int rem = gid & 4095;
      int q = rem >> 6, p = rem & 63;
      int ii = ((p >> 3) << 3) + (q >> 3);
      int jj = ((p & 7) << 3) + (q & 7);
      float v = tbl[ridx[ii * 64 + jj]][h];
      biasTb[gid] = f2bf(16.f / (1.f + expf(-v)));
    }
    return;
  }

  const int h = bid >> 2, t = bid & 3;
  const int wid = tid >> 6, lane = tid & 63;
  const int l15 = lane & 15, lk4 = (lane >> 4) << 2, lk8 = (lane >> 4) << 3;
  const f32x4 zf4 = {0.f, 0.f, 0.f, 0.f};

  f32x4 acc[2][8];
  #pragma unroll
  for (int mm = 0; mm < 2; ++mm)
    #pragma unroll
    for (int nn = 0; nn < 8; ++nn) acc[mm][nn] = zf4;

  if (t < 3) {
    const float* A = (t == 2) ? Wk : Wq;
    const float* B = (t == 0) ? Wk : ((t == 1) ? Wq : Wk);
    f32x4 accq[2] = {zf4, zf4};
    for (int ks = 0; ks < 12; ++ks) {
      const int koff = h * 384 + ks * 32 + lk8;
      bf16x8 a[2], bw[8];
      #pragma unroll
      for (int mm = 0; mm < 2; ++mm)
        a[mm] = ld_bf8(&A[(size_t)(wid * 32 + mm * 16 + l15) * 1536 + koff]);
      #pragma unroll
      for (int nn = 0; nn < 8; ++nn)
        bw[nn] = ld_bf8(&B[(size_t)(nn * 16 + l15) * 1536 + koff]);
      #pragma unroll
      for (int nn = 0; nn < 8; ++nn)
        #pragma unroll
        for (int mm = 0; mm < 2; ++mm)
          acc[mm][nn] = MFMA(a[mm], bw[nn], acc[mm][nn]);
      if (t >= 1) {
        bf16x8 bq = (l15 == 0) ? ld_bf8(&Qb[koff]) : zero_bf8();
        #pragma unroll
        for (int mm = 0; mm < 2; ++mm) accq[mm] = MFMA(a[mm], bq, accq[mm]);
      }
    }
    u16* dst = BigB + (size_t)((h * 3 + t) * 128) * 128;
    #pragma unroll
    for (int mm = 0; mm < 2; ++mm) {
      const int k0 = wid * 32 + mm * 16 + lk4;
      #pragma unroll
      for (int nn = 0; nn < 8; ++nn) {
        s16x4 u;
        u[0] = (short)f2bf(acc[mm][nn][0]); u[1] = (short)f2bf(acc[mm][nn][1]);
        u[2] = (short)f2bf(acc[mm][nn][2]); u[3] = (short)f2bf(acc[mm][nn][3]);
        *(s16x4*)&dst[(nn * 16 + l15) * 128 + k0] = u;
      }
    }
    if (t >= 1 && l15 == 0) {
      float* tgt = (t == 1) ? augGq : augM;
      const float sc = (t == 1) ? 2.f : 1.f;
      #pragma unroll
      for (int mm = 0; mm < 2; ++mm)
        #pragma unroll
        for (int r = 0; r < 4; ++r)
          tgt[h * 128 + wid * 32 + mm * 16 + lk4 + r] = sc * accq[mm][r];
    }
  } else {
    f32x4 accv[8];
    #pragma unroll
    for (int nn = 0; nn < 8; ++nn) accv[nn] = zf4;
    for (int chunk = 0; chunk < 2; ++chunk) {
      __syncthreads();
      // stage Wa_h^T chunk: a' in [0,192), coalesced float4 reads
      for (int it = 0; it < 24; ++it) {
        int idx = it * 256 + tid;                // 6144 float4
        int a = idx >> 5;                        // 0..191
        int c4 = (idx & 31) << 2;                // 0..124
        const float4 v = *(const float4*)&Wa[(size_t)(h * 384 + chunk * 192 + a) * 128 + c4];
        sWaT[(c4 + 0) * 200 + a] = f2bf(v.x);
        sWaT[(c4 + 1) * 200 + a] = f2bf(v.y);
        sWaT[(c4 + 2) * 200 + a] = f2bf(v.z);
        sWaT[(c4 + 3) * 200 + a] = f2bf(v.w);
      }
      __syncthreads();
      for (int ks2 = 0; ks2 < 6; ++ks2) {
        const int koff = h * 384 + chunk * 192 + ks2 * 32 + lk8;
        const int lkoff = ks2 * 32 + lk8;
        bf16x8 a[2], bw[8];
        #pragma unroll
        for (int mm = 0; mm < 2; ++mm)
          a[mm] = ld_bf8(&Wv[(size_t)(wid * 32 + mm * 16 + l15) * 1536 + koff]);
        #pragma unroll
        for (int nn = 0; nn < 8; ++nn)
          bw[nn] = *(const bf16x8*)&sWaT[(nn * 16 + l15) * 200 + lkoff];
        #pragma unroll
        for (int nn = 0; nn < 8; ++nn)
          #pragma unroll
          for (int mm = 0; mm < 2; ++mm)
            acc[mm][nn] = MFMA(a[mm], bw[nn], acc[mm][nn]);
        if (wid == 0) {
          bf16x8 av = (l15 == 0) ? ld_bf8(&Vb[koff]) : zero_bf8();
          #pragma unroll
          for (int nn = 0; nn < 8; ++nn) accv[nn] = MFMA(av, bw[nn], accv[nn]);
        }
      }
    }
    u16* dst = NT + (size_t)(h * 128) * 128;
    #pragma unroll
    for (int mm = 0; mm < 2; ++mm) {
      const int k0 = wid * 32 + mm * 16 + lk4;
      #pragma unroll
      for (int nn = 0; nn < 8; ++nn) {
        s16x4 u;
        u[0] = (short)f2bf(acc[mm][nn][0]); u[1] = (short)f2bf(acc[mm][nn][1]);
        u[2] = (short)f2bf(acc[mm][nn][2]); u[3] = (short)f2bf(acc[mm][nn][3]);
        *(s16x4*)&dst[(nn * 16 + l15) * 128 + k0] = u;
      }
    }
    if (wid == 0 && lane < 16) {
      #pragma unroll
      for (int nn = 0; nn < 8; ++nn)
        w4[h * 128 + nn * 16 + lane] = accv[nn][0];
    }
  }
}

// ---------------- main fused kernel ----------------
// 1 block = 2 windows. 1024 threads = 16 waves (wave>>3 = window). 129 KB dyn LDS.
// Per window (8 waves), per head:
//  X = {out += P_{h-1} EN_{h-1}; Z = G E^T (diag partials); T1 = E M^T + augM}
//  Y = {S = T1 E^T -> P; EN = E N + w4 (transposed store)}
__global__ __launch_bounds__(1024, 1) void k_msa(
    const float* __restrict__ E,
    const u16* __restrict__ BigB, const u16* __restrict__ NT,
    const u16* __restrict__ biasTb,
    const float* __restrict__ augM, const float* __restrict__ augGq,
    const float* __restrict__ w4, const float* __restrict__ cq4,
    const float* __restrict__ temp, const float* __restrict__ Ab,
    float* __restrict__ out) {
  extern __shared__ __align__(16) char lds[];
  u16* sEb    = (u16*)(lds);               // 2 x [64][136]
  u16* sT1b   = (u16*)(lds + 34816);       // 2 x [64][136]
  u16* sPb    = (u16*)(lds + 69632);       // 2 x [64][72]
  u16* sENTb  = (u16*)(lds + 88064);       // 2 x [128][72]
  float* sDqb = (float*)(lds + 124928);    // 2 x [4][64]
  float* sDkb = (float*)(lds + 126976);    // 2 x [4][64]

  const int tid = threadIdx.x;
  const int wid = tid >> 6;
  const int w   = wid >> 3;       // window index in block
  const int wv  = wid & 7;        // wave-in-window
  const int lane = tid & 63;
  const int l15 = lane & 15;
  const int lk4 = (lane >> 4) << 2;
  const int lk8 = (lane >> 4) << 3;
  const int mt = wv >> 1;         // PV/S row tile
  const int ch = wv & 1;          // PV col half
  const int j0 = ch * 32;         // S col base
  const int onc = wv << 4;        // T1/EN col strip

  u16* sE   = sEb + w * 8704;
  u16* sT1  = sT1b + w * 8704;
  u16* sP   = sPb + w * 4608;
  u16* sENT = sENTb + w * 9216;
  float* sDqp = sDqb + w * 256;
  float* sDkp = sDkb + w * 256;

  // ---- stage E for both windows (f32 -> bf16)
  {
    const float4* E4 = (const float4*)(E + (size_t)blockIdx.x * 16384);
    #pragma unroll
    for (int it = 0; it < 4; ++it) {
      int i = tid + it * 1024;                  // 4096 float4
      float4 v = E4[i];
      int ww = i >> 11;
      int idx = i & 2047;
      int row = idx >> 5, c = (idx & 31) << 2;
      s16x4 u;
      u[0] = (short)f2bf(v.x); u[1] = (short)f2bf(v.y);
      u[2] = (short)f2bf(v.z); u[3] = (short)f2bf(v.w);
      *(s16x4*)&sEb[ww * 8704 + row * 136 + c] = u;
    }
  }
  __syncthreads();

  const f32x4 zf4 = {0.f, 0.f, 0.f, 0.f};
  f32x4 oacc[4];
  #pragma unroll
  for (int n = 0; n < 4; ++n) oacc[n] = zf4;

  for (int h = 0; h < 4; ++h) {
    // ================= X phase =================
    if (h > 0) {
      #pragma unroll
      for (int ks = 0; ks < 2; ++ks) {
        const int koff = ks * 32 + lk8;
        bf16x8 a = *(const bf16x8*)&sP[(mt * 16 + l15) * 72 + koff];
        #pragma unroll
        for (int n = 0; n < 4; ++n) {
          bf16x8 bw = *(const bf16x8*)&sENT[(ch * 64 + n * 16 + l15) * 72 + koff];
          oacc[n] = MFMA(a, bw, oacc[n]);
        }
      }
    }
    // Z = G E^T; wave owns 32 G rows x all 64 cols
    {
      const int zt = (wv < 4) ? 1 : 2;
      const int rw = (wv & 3) * 32;
      const u16* G = BigB + (size_t)((h * 3 + zt) * 128 + rw) * 128;
      f32x4 z[2][4];
      #pragma unroll
      for (int mm = 0; mm < 2; ++mm)
        #pragma unroll
        for (int n = 0; n < 4; ++n) z[mm][n] = zf4;
      #pragma unroll
      for (int ks = 0; ks < 4; ++ks) {
        const int koff = ks * 32 + lk8;
        bf16x8 a0 = *(const bf16x8*)&G[(l15) * 128 + koff];
        bf16x8 a1 = *(const bf16x8*)&G[(16 + l15) * 128 + koff];
        #pragma unroll
        for (int n = 0; n < 4; ++n) {
          bf16x8 bw = *(const bf16x8*)&sE[(n * 16 + l15) * 136 + koff];
          z[0][n] = MFMA(a0, bw, z[0][n]);
          z[1][n] = MFMA(a1, bw, z[1][n]);
        }
      }
      float aq[2][4];
      #pragma unroll
      for (int mm = 0; mm < 2; ++mm)
        #pragma unroll
        for (int r = 0; r < 4; ++r)
          aq[mm][r] = (wv < 4) ? augGq[h * 128 + rw + mm * 16 + lk4 + r] : 0.f;
      #pragma unroll
      for (int n = 0; n < 4; ++n) {
        const int j = n * 16 + l15;
        float p = 0.f;
        #pragma unroll
        for (int mm = 0; mm < 2; ++mm)
          #pragma unroll
          for (int r = 0; r < 4; ++r)
            p = fmaf(z[mm][n][r] + aq[mm][r],
                     bf2f(sE[j * 136 + rw + mm * 16 + lk4 + r]), p);
        p += __shfl_xor(p, 16);
        p += __shfl_xor(p, 32);
        if (lane < 16) {
          if (wv < 4) sDqp[(wv & 3) * 64 + j] = p;
          else        sDkp[(wv & 3) * 64 + j] = p;
        }
      }
    }
    // T1 = E M^T + augM ; col strip per wave
    {
      const u16* M = BigB + (size_t)(h * 3 * 128) * 128;
      f32x4 t1[4];
      #pragma unroll
      for (int m = 0; m < 4; ++m) t1[m] = zf4;
      #pragma unroll
      for (int ks = 0; ks < 4; ++ks) {
        const int koff = ks * 32 + lk8;
        bf16x8 bw = *(const bf16x8*)&M[(onc + l15) * 128 + koff];
        #pragma unroll
        for (int m = 0; m < 4; ++m) {
          bf16x8 a = *(const bf16x8*)&sE[(m * 16 + l15) * 136 + koff];
          t1[m] = MFMA(a, bw, t1[m]);
        }
      }
      const float ta = augM[h * 128 + onc + l15];
      const int col = onc + l15;
      #pragma unroll
      for (int m = 0; m < 4; ++m)
        #pragma unroll
        for (int r = 0; r < 4; ++r)
          sT1[(m * 16 + lk4 + r) * 136 + col] = f2bf(t1[m][r] + ta);
    }
    __syncthreads();
    // ================= Y phase =================
    {
      // S = T1 E^T (K=128)
      f32x4 s2[2] = {zf4, zf4};
      #pragma unroll
      for (int ks = 0; ks < 4; ++ks) {
        const int koff = ks * 32 + lk8;
        bf16x8 a = *(const bf16x8*)&sT1[(mt * 16 + l15) * 136 + koff];
        #pragma unroll
        for (int n = 0; n < 2; ++n) {
          bf16x8 bw = *(const bf16x8*)&sE[(j0 + n * 16 + l15) * 136 + koff];
          s2[n] = MFMA(a, bw, s2[n]);
        }
      }
      // EN = E N + w4 (K=128)
      const u16* Nt = NT + (size_t)(h * 128) * 128;
      f32x4 en[4];
      #pragma unroll
      for (int m = 0; m < 4; ++m) en[m] = zf4;
      #pragma unroll
      for (int ks = 0; ks < 4; ++ks) {
        const int koff = ks * 32 + lk8;
        bf16x8 bw = *(const bf16x8*)&Nt[(onc + l15) * 128 + koff];
        #pragma unroll
        for (int m = 0; m < 4; ++m) {
          bf16x8 a = *(const bf16x8*)&sE[(m * 16 + l15) * 136 + koff];
          en[m] = MFMA(a, bw, en[m]);
        }
      }
      // P epilogue
      const float th = temp[h], cqh = cq4[h];
      const int i0 = mt * 16 + lk4;
      f32x4 dq = *(const f32x4*)&sDqp[0 * 64 + i0];
      dq += *(const f32x4*)&sDqp[1 * 64 + i0];
      dq += *(const f32x4*)&sDqp[2 * 64 + i0];
      dq += *(const f32x4*)&sDqp[3 * 64 + i0];
      float qs[4];
      #pragma unroll
      for (int r = 0; r < 4; ++r)
        qs[r] = th / fmaxf(sqrtf(fmaxf(dq[r] + cqh, 0.f)), 1e-12f);
      #pragma unroll
      for (int n = 0; n < 2; ++n) {
        const int j = j0 + n * 16 + l15;
        const float dk = sDkp[0 * 64 + j] + sDkp[1 * 64 + j] +
                         sDkp[2 * 64 + j] + sDkp[3 * 64 + j];
        const float ki = 1.f / fmaxf(sqrtf(fmaxf(dk, 0.f)), 1e-12f);
        s16x4 bb = *(const s16x4*)&biasTb[h * 4096 + j * 64 + i0];
        #pragma unroll
        for (int r = 0; r < 4; ++r)
          sP[(i0 + r) * 72 + j] = f2bf(fmaf(s2[n][r] * qs[r], ki, bf2f((u16)bb[r])));
      }
      // EN epilogue: transposed store
      const float wc = w4[h * 128 + onc + l15];
      #pragma unroll
      for (int m = 0; m < 4; ++m) {
        s16x4 u;
        u[0] = (short)f2bf(en[m][0] + wc); u[1] = (short)f2bf(en[m][1] + wc);
        u[2] = (short)f2bf(en[m][2] + wc); u[3] = (short)f2bf(en[m][3] + wc);
        *(s16x4*)&sENT[(onc + l15) * 72 + m * 16 + lk4] = u;
      }
    }
    __syncthreads();
  }

  // ---- tail: out += P_3 EN_3 ; + bias ; plain f32 store
  {
    #pragma unroll
    for (int ks = 0; ks < 2; ++ks) {
      const int koff = ks * 32 + lk8;
      bf16x8 a = *(const bf16x8*)&sP[(mt * 16 + l15) * 72 + koff];
      #pragma unroll
      for (int n = 0; n < 4; ++n) {
        bf16x8 bw = *(const bf16x8*)&sENT[(ch * 64 + n * 16 + l15) * 72 + koff];
        oacc[n] = MFMA(a, bw, oacc[n]);
      }
    }
    float* ob = out + ((size_t)blockIdx.x * 2 + w) * 8192;
    #pragma unroll
    for (int n = 0; n < 4; ++n) {
      const int col = ch * 64 + n * 16 + l15;
      const float bv = Ab[col];
      #pragma unroll
      for (int r = 0; r < 4; ++r)
        ob[(mt * 16 + lk4 + r) * 128 + col] = oacc[n][r] + bv;
    }
  }
}

// ---------------- host ----------------
extern "C" void kernel_launch(void* const* d_in, const int* in_sizes, int n_in,
                              void* d_out, int out_size, void* d_ws, size_t ws_size,
                              hipStream_t stream) {
  const float* E    = (const float*)d_in[0];
  const float* rpos = (const float*)d_in[1];
  const int*   ridx = (const int*)d_in[2];
  const float* Wq   = (const float*)d_in[3];
  const float* Qb   = (const float*)d_in[4];
  const float* Wk   = (const float*)d_in[5];
  const float* Wv   = (const float*)d_in[6];
  const float* Vb   = (const float*)d_in[7];
  const float* Wa   = (const float*)d_in[8];
  const float* Ab   = (const float*)d_in[9];
  const float* w1   = (const float*)d_in[10];
  const float* b1   = (const float*)d_in[11];
  const float* w2   = (const float*)d_in[12];
  const float* ls   = (const float*)d_in[13];

  char* ws = (char*)d_ws;
  u16* BigB    = (u16*)(ws + 0);         // 4*3*128*128*2 = 393216
  u16* NT      = (u16*)(ws + 393216);    // 4*128*128*2   = 131072
  u16* biasTb  = (u16*)(ws + 524288);    // 16384*2       = 32768
  float* augM  = (float*)(ws + 557056);  // 512*4
  float* augGq = (float*)(ws + 559104);  // 512*4
  float* w4    = (float*)(ws + 561152);  // 512*4
  float* cq4   = (float*)(ws + 563200);  // 16
  float* temp  = (float*)(ws + 563264);  // 16

  static bool attr_set = false;
  if (!attr_set) {
    hipFuncSetAttribute((const void*)k_msa,
                        hipFuncAttributeMaxDynamicSharedMemorySize, 129024);
    attr_set = true;
  }

  k_prep<<<17, 256, 0, stream>>>(Wq, Wk, Wv, Wa, Qb, Vb, rpos, w1, b1, w2,
                                 ls, ridx, BigB, NT, biasTb, augM, augGq,
                                 w4, cq4, temp);
  k_msa<<<512, 1024, 129024, stream>>>(E, BigB, NT, biasTb, augM, augGq, w4,
                                       cq4, temp, Ab, (float*)d_out);
}